// Round 7
// baseline (53.138 us; speedup 1.0000x reference)
//
#include <hip/hip_runtime.h>
#include <hip/hip_bf16.h>

// out[b][o] = sum_{i,m} a0[b,i]*D[b,m]*T[i][m][o],  D[b,m]=a1*a2*a3, m=(j,k,l)
// K = 33^4 streamed once through v_mfma_f32_32x32x16_bf16.
// 4494 INDEPENDENT one-wave blocks: block=(chunk c, i-half h); cheap prologue
// (D precomputed by k_pre) so doubling waves doesn't double prologue work.
#define HSZ 32
#define HP1 33
#define M3 35937            // 33^3
#define M3P 35952           // padded to 2247*16
#define TI_STRIDE 1149984   // 33^3 * 32 floats (T stride over i)
#define NCHUNK 2247
#define NBLK (2 * NCHUNK)   // 4494
#define RED_BLOCKS 64
#define RED_PER 71          // 64*71 = 4544 >= 4494

// ws layout (floats):
//   a0T   @ 0        : 33*32                 (row 32 = 1.0 bias)
//   D     @ 2048     : 32*35952 = 1,150,464
//   tiles @ 1154048  : 4494*1024 = 4,601,856   total ~23 MB
#define OFF_A0T   0
#define OFF_D     2048
#define OFF_TILES 1154048

typedef short bf16x8 __attribute__((ext_vector_type(8)));
typedef float f32x16 __attribute__((ext_vector_type(16)));

__device__ inline short f2bf(float f) {
  __hip_bfloat16 h = __float2bfloat16(f);  // RTNE, pairs into v_cvt_pk
  return __builtin_bit_cast(short, h);
}

// k_pre: D[b][m] = a1*a2*a3 (0 in pad), a0T[i*32+b], zero d_out.
__global__ __launch_bounds__(256) void k_pre(const float* __restrict__ nh,
                                             float* __restrict__ a0T,
                                             float* __restrict__ D,
                                             float* __restrict__ out) {
  const int b = blockIdx.y;
  const int m = blockIdx.x * 256 + threadIdx.x;
  if (m < M3P) {
    float v = 0.f;
    if (m < M3) {
      const int j = m / 1089;
      const int r = m - j * 1089;
      const int k = r / 33;
      const int l = r - k * 33;
      const float a1 = (j < HSZ) ? nh[(b * 4 + 1) * HSZ + j] : 1.0f;
      const float a2 = (k < HSZ) ? nh[(b * 4 + 2) * HSZ + k] : 1.0f;
      const float a3 = (l < HSZ) ? nh[(b * 4 + 3) * HSZ + l] : 1.0f;
      v = a1 * a2 * a3;
    }
    D[(size_t)b * M3P + m] = v;
  }
  if (blockIdx.x == 0 && threadIdx.x < HP1) {
    const int i = threadIdx.x;
    a0T[i * 32 + b] = (i < HSZ) ? nh[b * 128 + i] : 1.0f;
  }
  if (blockIdx.x == 1 && b == 0) {
    ((float4*)out)[threadIdx.x] = make_float4(0.f, 0.f, 0.f, 0.f);
  }
}

// k_main: one wave per block. lane l: bo=l&31 (b for A / o for B), g=l>>5.
// h = blk/NCHUNK selects i-rows [0,16) or [16,33); c = chunk -> m in [16c,16c+16)
__global__ __launch_bounds__(64) void k_main(const float* __restrict__ T,
                                             const float* __restrict__ a0T,
                                             const float* __restrict__ D,
                                             float* __restrict__ tiles) {
  const int blk = (int)blockIdx.x;
  const int h = (blk >= NCHUNK) ? 1 : 0;
  const int c = blk - h * NCHUNK;
  const int l = (int)threadIdx.x;
  const int bo = l & 31;
  const int g = l >> 5;
  const int m0 = c * 16;
  const int iB = h ? 16 : 0;

  // cheap prologue: df from precomputed D (pad rows are 0), T column offsets
  const float* dp = D + (size_t)bo * M3P + m0 + 8 * g;
  float df[8];
  *(float4*)(df)     = *(const float4*)(dp);
  *(float4*)(df + 4) = *(const float4*)(dp + 4);
  int ioff[8];
#pragma unroll
  for (int e = 0; e < 8; ++e) {
    const int mm = m0 + 8 * g + e;
    const int mc = (mm < M3) ? mm : (M3 - 1);  // clamp; df=0 there anyway
    ioff[e] = mc * 32 + bo;
  }

#define LOADT(buf, av, row)                               \
  {                                                       \
    const float* Tp = T + (size_t)(row) * TI_STRIDE;      \
    _Pragma("unroll")                                     \
    for (int e = 0; e < 8; ++e) buf[e] = Tp[ioff[e]];     \
    av = a0T[(row) * 32 + bo];                            \
  }
#define COMP(buf, av)                                                      \
  {                                                                        \
    bf16x8 af, bfr;                                                        \
    _Pragma("unroll")                                                      \
    for (int e = 0; e < 8; ++e) {                                          \
      af[e] = f2bf((av) * df[e]);                                          \
      bfr[e] = f2bf(buf[e]);                                               \
    }                                                                      \
    acc = __builtin_amdgcn_mfma_f32_32x32x16_bf16(af, bfr, acc, 0, 0, 0);  \
  }

  f32x16 acc = {};
  float t0[8], t1[8], t2[8];
  float av0, av1, av2;
  // dist-2, 3-buffer pipeline over this wave's 16 (h=0) or 17 (h=1) rows
  LOADT(t0, av0, iB + 0);
  LOADT(t1, av1, iB + 1);
#pragma unroll 1
  for (int k3 = 0; k3 < 4; ++k3) {  // computes rows iB..iB+11, loads to iB+13
    const int i = iB + 3 * k3;
    LOADT(t2, av2, i + 2);
    COMP(t0, av0);
    LOADT(t0, av0, i + 3);
    COMP(t1, av1);
    LOADT(t1, av1, i + 4);
    COMP(t2, av2);
  }
  // t0 = row iB+12, t1 = row iB+13
  if (h == 0) {
    LOADT(t2, av2, 14);
    COMP(t0, av0);  // 12
    LOADT(t0, av0, 15);
    COMP(t1, av1);  // 13
    COMP(t2, av2);  // 14
    COMP(t0, av0);  // 15
  } else {
    LOADT(t2, av2, 30);
    COMP(t0, av0);  // 28
    LOADT(t0, av0, 31);
    COMP(t1, av1);  // 29
    LOADT(t1, av1, 32);
    COMP(t2, av2);  // 30
    COMP(t0, av0);  // 31
    COMP(t1, av1);  // 32 (bias row: a0T row 32 = 1.0)
  }
#undef LOADT
#undef COMP

  // private tile; C/D layout: col=lane&31, row=(r&3)+8*(r>>2)+4*(l>>5)
  float* tp = tiles + (size_t)blk * 1024;
#pragma unroll
  for (int r = 0; r < 16; ++r) {
    const int brow = (r & 3) + 8 * (r >> 2) + 4 * g;
    tp[brow * 32 + bo] = acc[r];
  }
}

// k_red: block q sums contiguous tiles [q*71, min(q*71+71, NBLK)).
__global__ __launch_bounds__(256) void k_red(const float* __restrict__ tiles,
                                             float* __restrict__ out) {
  const int q = (int)blockIdx.x;
  const int tid = (int)threadIdx.x;
  const int tBeg = q * RED_PER;
  const int tEnd = (tBeg + RED_PER < NBLK) ? (tBeg + RED_PER) : NBLK;
  float4 s0 = make_float4(0.f, 0.f, 0.f, 0.f);
  float4 s1 = make_float4(0.f, 0.f, 0.f, 0.f);
  int t = tBeg;
  for (; t + 1 < tEnd; t += 2) {
    const float4 v0 = *(const float4*)(tiles + (size_t)t * 1024 + tid * 4);
    const float4 v1 = *(const float4*)(tiles + (size_t)(t + 1) * 1024 + tid * 4);
    s0.x += v0.x; s0.y += v0.y; s0.z += v0.z; s0.w += v0.w;
    s1.x += v1.x; s1.y += v1.y; s1.z += v1.z; s1.w += v1.w;
  }
  if (t < tEnd) {
    const float4 v0 = *(const float4*)(tiles + (size_t)t * 1024 + tid * 4);
    s0.x += v0.x; s0.y += v0.y; s0.z += v0.z; s0.w += v0.w;
  }
  atomicAdd(&out[tid * 4 + 0], s0.x + s1.x);
  atomicAdd(&out[tid * 4 + 1], s0.y + s1.y);
  atomicAdd(&out[tid * 4 + 2], s0.z + s1.z);
  atomicAdd(&out[tid * 4 + 3], s0.w + s1.w);
}

extern "C" void kernel_launch(void* const* d_in, const int* in_sizes, int n_in,
                              void* d_out, int out_size, void* d_ws, size_t ws_size,
                              hipStream_t stream) {
  const float* nh = (const float*)d_in[0];  // [32,4,32]
  const float* T  = (const float*)d_in[1];  // [33,33,33,33,32]
  float* out = (float*)d_out;               // [32,32] fp32
  float* ws = (float*)d_ws;
  float* a0T   = ws + OFF_A0T;
  float* D     = ws + OFF_D;
  float* tiles = ws + OFF_TILES;

  k_pre<<<dim3(141, 32), 256, 0, stream>>>(nh, a0T, D, out);
  k_main<<<NBLK, 64, 0, stream>>>(T, a0T, D, tiles);
  k_red<<<RED_BLOCKS, 256, 0, stream>>>(tiles, out);
}

// Round 8
// 43.354 us; speedup vs baseline: 1.2257x; 1.2257x over previous
//
#include <hip/hip_runtime.h>

// Problem constants
#define HSZ 32
#define HP1 33
#define M3 35937            // 33^3 (flattened j,k,l)
#define M3P 35952           // padded to multiple of 16 (2247*16)
#define TI_STRIDE 1149984   // 33^3 * 32 floats (stride of T over i)
#define NBLK 2247           // M3P / 16, one wave per block
#define NT 64               // partial output tiles (atomic contention 2247/64 ~ 35)

// ws layout (bytes):
//   a0T   @ 0        : 33*32 floats (a0 transposed, [i][b])
//   D     @ 8192     : 32*35952 floats = 4,601,856 B (zero-padded tail)
//   tiles @ 4610048  : 64*1024 floats = 262,144 B      total ~4.9 MB
#define OFF_A0T   0
#define OFF_D     8192
#define OFF_TILES 4610048

typedef short bf16x8 __attribute__((ext_vector_type(8)));
typedef float f32x16 __attribute__((ext_vector_type(16)));

__device__ inline short f2bf(float f) {
  unsigned u = __builtin_bit_cast(unsigned, f);
  u += 0x7FFFu + ((u >> 16) & 1u);   // round-to-nearest-even
  return (short)(u >> 16);
}

// Prologue: D[b][m] = a1*a2*a3 (0 in pad), a0T[i][b], zero the partial tiles.
__global__ __launch_bounds__(256) void k_pre(const float* __restrict__ nh,
                                             float* __restrict__ a0T,
                                             float* __restrict__ D,
                                             float* __restrict__ tiles) {
  const int b = blockIdx.y;
  const int m = blockIdx.x * 256 + threadIdx.x;
  if (m < M3P) {
    float v = 0.f;
    if (m < M3) {
      const int j = m / 1089;
      const int r = m - j * 1089;
      const int k = r / 33;
      const int l = r - k * 33;
      const float a1 = (j < HSZ) ? nh[(b * 4 + 1) * HSZ + j] : 1.0f;
      const float a2 = (k < HSZ) ? nh[(b * 4 + 2) * HSZ + k] : 1.0f;
      const float a3 = (l < HSZ) ? nh[(b * 4 + 3) * HSZ + l] : 1.0f;
      v = a1 * a2 * a3;
    }
    D[(size_t)b * M3P + m] = v;
  }
  if (blockIdx.x == 0 && threadIdx.x < HP1) {
    const int i = threadIdx.x;
    a0T[i * 32 + b] = (i < HSZ) ? nh[(b * 4 + 0) * HSZ + i] : 1.0f;
  }
  if (b == 1 && blockIdx.x < 64) {  // 64 blocks * 256 threads * 16B = 256 KB
    ((float4*)tiles)[blockIdx.x * 256 + threadIdx.x] =
        make_float4(0.f, 0.f, 0.f, 0.f);
  }
}

// Main: one wave per block; block owns m-chunk [m0, m0+16).
// acc[32b x 32o] += sum_i sum_{mm} (a0[b,i]*D[b,mm]) * T[i][mm][o] via
// v_mfma_f32_32x32x16_bf16. T is read exactly once device-wide, coalesced.
__global__ __launch_bounds__(64) void k_main(const float* __restrict__ T,
                                             const float* __restrict__ a0T,
                                             const float* __restrict__ D,
                                             float* __restrict__ tiles) {
  const int blk = blockIdx.x;
  const int m0 = blk * 16;
  const int l = (int)threadIdx.x;  // 0..63
  const int bo = l & 31;           // A row (b) / B col (o)
  const int g = l >> 5;            // k-group: k = 8*g + e

  // A-side D fragment (fp32, reused across all 33 i): D[bo][m0+8g+e]
  const float* dp = D + (size_t)bo * M3P + m0 + 8 * g;
  float df[8];
  *(float4*)(df)     = *(const float4*)(dp);
  *(float4*)(df + 4) = *(const float4*)(dp + 4);

  // Per-lane T element offsets for the 8 k's (clamped in the zero-padded tail)
  size_t toff[8];
#pragma unroll
  for (int e = 0; e < 8; ++e) {
    int mm = m0 + 8 * g + e;
    if (mm > M3 - 1) mm = M3 - 1;  // A-frag is 0 there (D pad), value ignored
    toff[e] = (size_t)mm * 32 + bo;
  }

  f32x16 acc = {};

  // software pipeline: loads for i+1 in flight during cvt+MFMA of i
  float tv[8];
#pragma unroll
  for (int e = 0; e < 8; ++e) tv[e] = T[toff[e]];
  float a0c = a0T[bo];

  for (int i = 0; i < HP1; ++i) {
    float tn[8];
    float a0n = 0.f;
    if (i < HP1 - 1) {
      const float* Tn = T + (size_t)(i + 1) * TI_STRIDE;
#pragma unroll
      for (int e = 0; e < 8; ++e) tn[e] = Tn[toff[e]];
      a0n = a0T[(i + 1) * 32 + bo];
    }
    bf16x8 af, bfr;
#pragma unroll
    for (int e = 0; e < 8; ++e) {
      af[e]  = f2bf(a0c * df[e]);
      bfr[e] = f2bf(tv[e]);
    }
    acc = __builtin_amdgcn_mfma_f32_32x32x16_bf16(af, bfr, acc, 0, 0, 0);
#pragma unroll
    for (int e = 0; e < 8; ++e) tv[e] = tn[e];
    a0c = a0n;
  }

  // Accumulate into one of NT partial tiles.
  // C/D layout (verified m74/m101): col=lane&31, row=(r&3)+8*(r>>2)+4*(lane>>5)
  float* tp = tiles + (size_t)(blk & (NT - 1)) * 1024;
#pragma unroll
  for (int r = 0; r < 16; ++r) {
    const int brow = (r & 3) + 8 * (r >> 2) + 4 * g;
    atomicAdd(tp + brow * 32 + bo, acc[r]);
  }
}

// Final reduce: out[idx] = sum over NT tiles.
__global__ __launch_bounds__(256) void k_red(const float* __restrict__ tiles,
                                             float* __restrict__ out) {
  const int idx = blockIdx.x * 256 + (int)threadIdx.x;
  float s = 0.f;
  for (int t = 0; t < NT; ++t) s += tiles[(size_t)t * 1024 + idx];
  out[idx] = s;
}

extern "C" void kernel_launch(void* const* d_in, const int* in_sizes, int n_in,
                              void* d_out, int out_size, void* d_ws, size_t ws_size,
                              hipStream_t stream) {
  const float* nh = (const float*)d_in[0];  // [32,4,32]
  const float* T  = (const float*)d_in[1];  // [33,33,33,33,32]
  float* out = (float*)d_out;               // [32,32] fp32
  char* ws = (char*)d_ws;
  float* a0T   = (float*)(ws + OFF_A0T);
  float* D     = (float*)(ws + OFF_D);
  float* tiles = (float*)(ws + OFF_TILES);

  k_pre<<<dim3(141, 32), 256, 0, stream>>>(nh, a0T, D, tiles);
  k_main<<<NBLK, 64, 0, stream>>>(T, a0T, D, tiles);
  k_red<<<4, 256, 0, stream>>>(tiles, out);
}